// Round 13
// baseline (134.281 us; speedup 1.0000x reference)
//
#include <hip/hip_runtime.h>
#include <hip/hip_bf16.h>
#include <math.h>

// Problem dims (fixed by reference)
#define B   32
#define P   196      // hw tokens (14x14)
#define C   768
#define NC  4096
#define HH  14
#define KSPLIT 24    // 768 / 32
#define M6  6272     // B*P
// Packed sub-slice layout: [kb(24)][rg(rows/32)][s(4)][r(32)][e(8)]
//   element (row, k): kb=k>>5, rg=row>>5, s=(k>>3)&3, r=row&31, e=k&7.
//   One (kb,rg) chunk = 1024 f16 = 2 KB contiguous; LDS fragment reads are
//   16 B row stride -> bank-conflict-free.
#define TOK_KB 200704        // 196 * 1024 elements per kb
#define WT_KB  24576         // 24 * 1024 elements per kb

typedef _Float16 half8 __attribute__((ext_vector_type(8)));
typedef _Float16 half4 __attribute__((ext_vector_type(4)));
typedef float f32x4 __attribute__((ext_vector_type(4)));

#define GLOAD_LDS16(g, l)                                                      \
    __builtin_amdgcn_global_load_lds(                                          \
        (const __attribute__((address_space(1))) void*)(g),                    \
        (__attribute__((address_space(3))) void*)(l), 16, 0, 0)

// ---------------------------------------------------------------------------
// K1: SpaceSelfAware + space_fusion + residual.  (R12 version, 16-ch blocks)
// ---------------------------------------------------------------------------
__global__ __launch_bounds__(256) void k_ssa(const float* __restrict__ t,
                                             float* __restrict__ pre) {
    const int b = blockIdx.y, c0 = blockIdx.x * 16;
    __shared__ float xp_[256 * 16];        // [(i+2)*16 + (j+1)][cc]  16 KB
    __shared__ float part[4][9][16];
    __shared__ float inv_norm[9][16];
    const int tid = threadIdx.x;
    const int cc = tid & 15, g = tid >> 4, wv = tid >> 6;

#pragma unroll
    for (int q = 0; q < 16; ++q) xp_[q * 256 + tid] = 0.0f;
    __syncthreads();

    for (int idx = tid; idx < 784; idx += 256) {
        const int p = idx >> 2, c = (idx & 3) * 4;
        const int i = p / HH, j = p % HH;
        *(float4*)&xp_[((i + 2) * 16 + (j + 1)) * 16 + c] =
            *(const float4*)&t[((size_t)b * P + p) * C + c0 + c];
    }
    __syncthreads();

    float s[9] = {};
    {
        int i = 0, j = g;
        if (j >= HH) { j -= HH; i = 1; }
        for (int p = g; p < P; p += 16) {
            const int base = ((i + 2) * 16 + (j + 1)) * 16 + cc;
            const float xp = xp_[base];
            const float xp2 = xp * xp;
#pragma unroll
            for (int k = 0; k < 9; ++k) {
                const int off = ((k / 3) - 2) * 16 + (k % 3) - 1;  // const
                const float nb = xp_[base + off * 16];
                s[k] += xp2 * nb * nb;
            }
            j += 2; ++i;
            if (j >= HH) { j -= HH; ++i; }
        }
    }
#pragma unroll
    for (int k = 0; k < 9; ++k) {
        float r = s[k];
        r += __shfl_xor(r, 16);
        r += __shfl_xor(r, 32);
        s[k] = r;
    }
    if ((tid & 63) < 16) {
#pragma unroll
        for (int k = 0; k < 9; ++k) part[wv][k][cc] = s[k];
    }
    __syncthreads();
    if (tid < 144) {
        const int k = tid >> 4, c2 = tid & 15;
        const float t4 = part[0][k][c2] + part[1][k][c2] +
                         part[2][k][c2] + part[3][k][c2];
        inv_norm[k][c2] = 1.0f / fmaxf(sqrtf(t4), 1e-12f);
    }
    __syncthreads();

    float invn[9];
#pragma unroll
    for (int k = 0; k < 9; ++k) invn[k] = inv_norm[k][cc];

    {
        int i = 0, j = g;
        if (j >= HH) { j -= HH; i = 1; }
        for (int p = g; p < P; p += 16) {
            const int base = ((i + 2) * 16 + (j + 1)) * 16 + cc;
            const float xp = xp_[base];
            float acc = 0.0f;
#pragma unroll
            for (int k = 0; k < 9; ++k) {
                const int off = ((k / 3) - 2) * 16 + (k % 3) - 1;
                const float v = xp * xp_[base + off * 16];
                const float u = fmaxf(v * invn[k], 1e-6f);
                acc += u * u * u;
            }
            pre[((size_t)b * P + p) * C + c0 + cc] =
                cbrtf(acc * (1.0f / 9.0f)) + xp;
            j += 2; ++i;
            if (j >= HH) { j -= HH; ++i; }
        }
    }
}

// ---------------------------------------------------------------------------
// K2: L2 normalize each (b,p) row; write f16 tokens in packed layout.
// ---------------------------------------------------------------------------
__global__ __launch_bounds__(256) void k_rownorm(const float* __restrict__ in,
                                                 _Float16* __restrict__ outP) {
    const int row = blockIdx.x;               // b*P + p
    const float* r = in + (size_t)row * C;
    const int tid = threadIdx.x;
    float vals[3];
    float s = 0.0f;
#pragma unroll
    for (int q = 0; q < 3; ++q) {
        vals[q] = r[tid + q * 256];
        s += vals[q] * vals[q];
    }
    __shared__ float partial[4];
    __shared__ float inv;
    __shared__ _Float16 nrm[C];
#pragma unroll
    for (int off = 32; off > 0; off >>= 1) s += __shfl_xor(s, off);
    if ((tid & 63) == 0) partial[tid >> 6] = s;
    __syncthreads();
    if (tid == 0)
        inv = 1.0f / fmaxf(sqrtf(partial[0] + partial[1] + partial[2] + partial[3]), 1e-12f);
    __syncthreads();
#pragma unroll
    for (int q = 0; q < 3; ++q)
        nrm[tid + q * 256] = (_Float16)(vals[q] * inv);
    __syncthreads();
    if (tid < 96) {
        const half8 v = *(const half8*)&nrm[tid * 8];
        const int kb = tid >> 2, s8 = tid & 3;   // c = tid*8
        *(half8*)&outP[(size_t)kb * TOK_KB + (row >> 5) * 1024 + s8 * 256 +
                       (row & 31) * 8] = v;
    }
}

// ---------------------------------------------------------------------------
// K2b: weight pack: W (K x N) f32 -> WtP packed [kb][rg][s][r][8] f16
// ---------------------------------------------------------------------------
__global__ __launch_bounds__(256) void k_wt(const float* __restrict__ W,
                                            _Float16* __restrict__ WtP) {
    __shared__ float tt[32][33];
    const int k0 = blockIdx.x * 32, n0 = blockIdx.y * 32;   // kb = blockIdx.x
    const int r = threadIdx.x / 32, c = threadIdx.x % 32;
#pragma unroll
    for (int q = 0; q < 4; ++q)
        tt[r + q * 8][c] = W[(size_t)(k0 + r + q * 8) * C + n0 + c];
    __syncthreads();
    const int nl = threadIdx.x >> 3, h = threadIdx.x & 7;
    const int n = n0 + nl;
    half4 v;
#pragma unroll
    for (int j = 0; j < 4; ++j) v[j] = (_Float16)tt[h * 4 + j][nl];
    *(half4*)&WtP[(size_t)blockIdx.x * WT_KB + (n >> 5) * 1024 +
                  (h >> 1) * 256 + (n & 31) * 8 + (h & 1) * 4] = v;
}

// ---------------------------------------------------------------------------
// K3/K4: f16 MFMA GEMM, BARRIER-FREE per-wave private LDS pipelines.
// Block = 128M x 64N, 4 waves; wave w owns m-rows [wm, wm+32) x all 64 n.
// Each wave stages its OWN A chunk (64n x 32k, 4 KB) + B chunk (its 32m x
// 32k, 2 KB) per K-step via global_load_lds into private LDS, 3-deep,
// waiting only on its own counted vmcnt — NO s_barrier in the K-loop, so
// no convoy: waves drift and hide each other's latency.  24 K-steps,
// 8 MFMA/step/wave.  LDS 72 KB -> 2 blocks/CU (8 independent waves/CU).
// Packed chunks: staging is contiguous 1 KB loads; LDS fragment reads are
// 16 B row stride (conflict-free).  Grid 588 1-D, XCD swizzle (one m-row's
// 12 n-tiles per XCD -> Tok HBM-fetched once, W L2-resident).
// GELU=true: output packed f16.  GELU=false: f32 row-major.
// ---------------------------------------------------------------------------
template <bool GELU>
__global__ __launch_bounds__(256) void k_mfma_gemm(
    const _Float16* __restrict__ TokP,  // packed [24][196][4][32][8]  B-op
    const _Float16* __restrict__ WtP,   // packed [24][24][4][32][8]   A-op
    const float* __restrict__ bias,     // (N)
    void* __restrict__ Cout) {          // packed f16 (GELU) or f32 row-major
    __shared__ _Float16 lA[4][3][2048];   // [wave][stage][2 chunks]
    __shared__ _Float16 lB[4][3][1024];   // [wave][stage][1 chunk]
    const int tid = threadIdx.x;
    const int w = tid >> 6, l = tid & 63;
    const int l15 = l & 15, lk = l >> 4;

    // XCD swizzle: equal lid%8 (one XCD) covers one m-row's 12 n-tiles.
    const int lid = blockIdx.x;
    int vm, vn;
    if (lid < 576) { vm = (lid / 96) * 8 + (lid & 7); vn = (lid % 96) >> 3; }
    else           { vm = 48; vn = lid - 576; }
    const int m0 = vm * 128, n0 = vn * 64;
    const int wm = w * 32;

    f32x4 acc[4][2] = {};   // [fa over n][fb over m]

    const _Float16* srcA = WtP + (size_t)vn * 2048;          // + kb*WT_KB
    const _Float16* srcB = TokP + (size_t)(vm * 4 + w) * 1024;  // + kb*TOK_KB

#define ISSUE(tt_, st_)                                                        \
    {   const _Float16* sA = srcA + (size_t)(tt_) * WT_KB;                     \
        const _Float16* sB = srcB + (size_t)(tt_) * TOK_KB;                    \
        _Float16* dA = &lA[w][st_][0];                                         \
        _Float16* dB = &lB[w][st_][0];                                         \
        GLOAD_LDS16(sA + l * 8,        dA + l * 8);                            \
        GLOAD_LDS16(sA + 512 + l * 8,  dA + 512 + l * 8);                      \
        GLOAD_LDS16(sA + 1024 + l * 8, dA + 1024 + l * 8);                     \
        GLOAD_LDS16(sA + 1536 + l * 8, dA + 1536 + l * 8);                     \
        GLOAD_LDS16(sB + l * 8,        dB + l * 8);                            \
        GLOAD_LDS16(sB + 512 + l * 8,  dB + 512 + l * 8); }

    ISSUE(0, 0); ISSUE(1, 1); ISSUE(2, 2);   // 18 loads in flight / wave

    for (int t = 0; t < 24; ++t) {
        // own-wave stage-t loads complete; t+1, t+2 stay in flight
        if (t < 22)       asm volatile("s_waitcnt vmcnt(12)" ::: "memory");
        else if (t == 22) asm volatile("s_waitcnt vmcnt(6)" ::: "memory");
        else              asm volatile("s_waitcnt vmcnt(0)" ::: "memory");
        __builtin_amdgcn_sched_barrier(0);   // no ds_read above the wait

        const int st = t % 3;
        half8 af[4], bf2[2];
#pragma unroll
        for (int fa = 0; fa < 4; ++fa)
            af[fa] = *(const half8*)&lA[w][st][(fa >> 1) * 1024 + lk * 256 +
                                              ((fa & 1) * 16 + l15) * 8];
#pragma unroll
        for (int fb = 0; fb < 2; ++fb)
            bf2[fb] = *(const half8*)&lB[w][st][lk * 256 + (fb * 16 + l15) * 8];
#pragma unroll
        for (int fa = 0; fa < 4; ++fa)
#pragma unroll
            for (int fb = 0; fb < 2; ++fb)
                acc[fa][fb] = __builtin_amdgcn_mfma_f32_16x16x32_f16(
                    af[fa], bf2[fb], acc[fa][fb], 0, 0, 0);
        asm volatile("s_waitcnt lgkmcnt(0)" ::: "memory");  // frags read out
        __builtin_amdgcn_sched_barrier(0);
        if (t < 21) ISSUE(t + 3, st);        // refill own stage; no sync
    }
#undef ISSUE

    // epilogue: lane holds D[n = nb + r][m], r=0..3 consecutive n
#pragma unroll
    for (int fa = 0; fa < 4; ++fa) {
        const int nb = n0 + fa * 16 + lk * 4;
        const float4 bv = *(const float4*)&bias[nb];
#pragma unroll
        for (int fb = 0; fb < 2; ++fb) {
            const int m = m0 + wm + fb * 16 + l15;
            if (GELU) {
                half4 o;
#pragma unroll
                for (int rr = 0; rr < 4; ++rr) {
                    float v = acc[fa][fb][rr] + ((const float*)&bv)[rr];
                    v = 0.5f * v * (1.0f + erff(v * 0.70710678118654752f));
                    o[rr] = (_Float16)v;
                }
                *(half4*)&((_Float16*)Cout)[(size_t)(nb >> 5) * TOK_KB +
                                            (m >> 5) * 1024 +
                                            ((nb >> 3) & 3) * 256 +
                                            (m & 31) * 8 + (nb & 7)] = o;
            } else {
                float4 o;
#pragma unroll
                for (int rr = 0; rr < 4; ++rr)
                    ((float*)&o)[rr] = acc[fa][fb][rr] + ((const float*)&bv)[rr];
                *(float4*)&((float*)Cout)[(size_t)m * C + nb] = o;
            }
        }
    }
}

// ---------------------------------------------------------------------------
// K5: GeM over tokens: g[b,c] = (mean_p clip(x,1e-6)^3)^(1/3)
// ---------------------------------------------------------------------------
__global__ __launch_bounds__(256) void k_gempool(const float* __restrict__ tk,
                                                 float* __restrict__ g) {
    const int b = blockIdx.x / 3;
    const int c = (blockIdx.x % 3) * 256 + threadIdx.x;
    float s = 0.0f;
#pragma unroll 4
    for (int p = 0; p < P; ++p) {
        const float v = fmaxf(tk[((size_t)b * P + p) * C + c], 1e-6f);
        s += v * v * v;
    }
    g[b * C + c] = cbrtf(s * (1.0f / (float)P));
}

// ---------------------------------------------------------------------------
// K6a: head GEMM stage 1 (split-K).  grid (NC/64, KSPLIT) = 1536 blocks.
// ---------------------------------------------------------------------------
__global__ __launch_bounds__(256) void k_head1(const float* __restrict__ g,
                                               const float* __restrict__ W,
                                               float* __restrict__ partial) {
    const int n0 = blockIdx.x * 64;
    const int k0 = blockIdx.y * 32;
    __shared__ float gs[32][32];          // [b][kk]
    __shared__ float part[4][32][64];     // [q][b][c]
    const int tid = threadIdx.x;

    for (int idx = tid; idx < 32 * 32; idx += 256)
        gs[idx >> 5][idx & 31] = g[(idx >> 5) * C + k0 + (idx & 31)];
    __syncthreads();

    const int c = tid & 63, q = tid >> 6;
    float acc[32] = {};
#pragma unroll
    for (int kk = 0; kk < 8; ++kk) {
        const int k = q * 8 + kk;
        const float wv = W[(size_t)(k0 + k) * NC + n0 + c];
#pragma unroll
        for (int b = 0; b < 32; ++b) acc[b] += gs[b][k] * wv;
    }
#pragma unroll
    for (int b = 0; b < 32; ++b) part[q][b][c] = acc[b];
    __syncthreads();

    for (int o = tid; o < 32 * 64; o += 256) {
        const int b = o >> 6, cc = o & 63;
        const float v = part[0][b][cc] + part[1][b][cc] +
                        part[2][b][cc] + part[3][b][cc];
        partial[((size_t)blockIdx.y * 32 + b) * NC + n0 + cc] = v;
    }
}

// ---------------------------------------------------------------------------
// K6b: head GEMM stage 2: fixed-order sum of KSPLIT partials + bias.
// ---------------------------------------------------------------------------
__global__ __launch_bounds__(256) void k_head2(const float* __restrict__ partial,
                                               const float* __restrict__ hb,
                                               float* __restrict__ out) {
    const int n = blockIdx.x * 256 + threadIdx.x;
    const int b = blockIdx.y;
    float s = hb[n];
#pragma unroll
    for (int ks = 0; ks < KSPLIT; ++ks)
        s += partial[((size_t)ks * 32 + b) * NC + n];
    out[(size_t)b * NC + n] = s;
}

// ---------------------------------------------------------------------------
// K7: L2-normalize each batch row of out (4096) in place.
// ---------------------------------------------------------------------------
__global__ __launch_bounds__(256) void k_outnorm(float* __restrict__ out) {
    const int b = blockIdx.x;
    float* r = out + (size_t)b * NC;
    const int tid = threadIdx.x;
    float v[16];
    float s = 0.0f;
#pragma unroll
    for (int q = 0; q < 16; ++q) {
        v[q] = r[tid + q * 256];
        s += v[q] * v[q];
    }
    __shared__ float partial[4];
    __shared__ float inv;
#pragma unroll
    for (int off = 32; off > 0; off >>= 1) s += __shfl_xor(s, off);
    if ((tid & 63) == 0) partial[tid >> 6] = s;
    __syncthreads();
    if (tid == 0)
        inv = 1.0f / fmaxf(sqrtf(partial[0] + partial[1] + partial[2] + partial[3]), 1e-12f);
    __syncthreads();
#pragma unroll
    for (int q = 0; q < 16; ++q) r[tid + q * 256] = v[q] * inv;
}

// ---------------------------------------------------------------------------
extern "C" void kernel_launch(void* const* d_in, const int* in_sizes, int n_in,
                              void* d_out, int out_size, void* d_ws, size_t ws_size,
                              hipStream_t stream) {
    const float* patch  = (const float*)d_in[0];
    const float* fc1_w  = (const float*)d_in[1];
    const float* fc1_b  = (const float*)d_in[2];
    const float* fc2_w  = (const float*)d_in[3];
    const float* fc2_b  = (const float*)d_in[4];
    const float* head_w = (const float*)d_in[5];
    const float* head_b = (const float*)d_in[6];
    float* out = (float*)d_out;

    const size_t big = (size_t)B * P * C;        // 4,816,896 elements
    float*    pre  = (float*)d_ws;               // [big] f32; later reused as tok2
    _Float16* tokP = (_Float16*)(pre + big);     // [big] f16 packed
    _Float16* hdnP = tokP + big;                 // [big] f16 packed
    _Float16* wt1  = hdnP + big;                 // [768*768] f16 packed
    _Float16* wt2  = wt1 + C * C;                // [768*768] f16 packed
    float*    gbuf = (float*)(wt2 + C * C);      // [32*768] f32
    float*    hpart = gbuf + B * C;              // [KSPLIT*32*4096] f32
    float*    tok2 = pre;                        // reuse

    // K1: SSA + fusion + residual -> pre
    k_ssa<<<dim3(C / 16, B), dim3(256), 0, stream>>>(patch, pre);
    // weight packs (independent)
    k_wt<<<dim3(C / 32, C / 32), dim3(256), 0, stream>>>(fc1_w, wt1);
    k_wt<<<dim3(C / 32, C / 32), dim3(256), 0, stream>>>(fc2_w, wt2);
    // K2: channel L2 norm -> tokP (f16 packed)
    k_rownorm<<<dim3(B * P), dim3(256), 0, stream>>>(pre, tokP);
    // K3: fc1 + gelu -> hdnP (f16 packed)
    k_mfma_gemm<true><<<dim3(588), dim3(256), 0, stream>>>(
        tokP, wt1, fc1_b, hdnP);
    // K4: fc2 -> tok2 (f32 row-major)
    k_mfma_gemm<false><<<dim3(588), dim3(256), 0, stream>>>(
        hdnP, wt2, fc2_b, tok2);
    // K5: GeM over tokens -> gbuf
    k_gempool<<<dim3(B * 3), dim3(256), 0, stream>>>(tok2, gbuf);
    // K6: head GEMM, split-K two-stage -> out (pre-normalized)
    k_head1<<<dim3(NC / 64, KSPLIT), dim3(256), 0, stream>>>(gbuf, head_w, hpart);
    k_head2<<<dim3(NC / 256, B), dim3(256), 0, stream>>>(hpart, head_b, out);
    // K7: normalize rows of out
    k_outnorm<<<dim3(B), dim3(256), 0, stream>>>(out);
}

// Round 14
// 112.467 us; speedup vs baseline: 1.1940x; 1.1940x over previous
//
#include <hip/hip_runtime.h>
#include <hip/hip_bf16.h>
#include <math.h>

// Problem dims (fixed by reference)
#define B   32
#define P   196      // hw tokens (14x14)
#define C   768
#define NC  4096
#define HH  14
#define KSPLIT 24    // 768 / 32
#define M6  6272     // B*P
// Packed sub-slice layout: [kb(24)][rg(rows/32)][s(4)][r(32)][e(8)]
//   element (row, k): kb=k>>5, rg=row>>5, s=(k>>3)&3, r=row&31, e=k&7.
//   One (kb,rg) chunk = 1024 f16 = 2 KB contiguous; a fragment load from it
//   is 4 x 256 B segments (16 consecutive lanes per segment) -> coalesced.
#define TOK_KB 200704        // 196 * 1024 elements per kb
#define WT_KB  24576         // 24 * 1024 elements per kb

typedef _Float16 half8 __attribute__((ext_vector_type(8)));
typedef _Float16 half4 __attribute__((ext_vector_type(4)));
typedef float f32x4 __attribute__((ext_vector_type(4)));

// ---------------------------------------------------------------------------
// K1: SpaceSelfAware + space_fusion + residual.  (R12/R13 version)
// ---------------------------------------------------------------------------
__global__ __launch_bounds__(256) void k_ssa(const float* __restrict__ t,
                                             float* __restrict__ pre) {
    const int b = blockIdx.y, c0 = blockIdx.x * 16;
    __shared__ float xp_[256 * 16];        // [(i+2)*16 + (j+1)][cc]  16 KB
    __shared__ float part[4][9][16];
    __shared__ float inv_norm[9][16];
    const int tid = threadIdx.x;
    const int cc = tid & 15, g = tid >> 4, wv = tid >> 6;

#pragma unroll
    for (int q = 0; q < 16; ++q) xp_[q * 256 + tid] = 0.0f;
    __syncthreads();

    for (int idx = tid; idx < 784; idx += 256) {
        const int p = idx >> 2, c = (idx & 3) * 4;
        const int i = p / HH, j = p % HH;
        *(float4*)&xp_[((i + 2) * 16 + (j + 1)) * 16 + c] =
            *(const float4*)&t[((size_t)b * P + p) * C + c0 + c];
    }
    __syncthreads();

    float s[9] = {};
    {
        int i = 0, j = g;
        if (j >= HH) { j -= HH; i = 1; }
        for (int p = g; p < P; p += 16) {
            const int base = ((i + 2) * 16 + (j + 1)) * 16 + cc;
            const float xp = xp_[base];
            const float xp2 = xp * xp;
#pragma unroll
            for (int k = 0; k < 9; ++k) {
                const int off = ((k / 3) - 2) * 16 + (k % 3) - 1;  // const
                const float nb = xp_[base + off * 16];
                s[k] += xp2 * nb * nb;
            }
            j += 2; ++i;
            if (j >= HH) { j -= HH; ++i; }
        }
    }
#pragma unroll
    for (int k = 0; k < 9; ++k) {
        float r = s[k];
        r += __shfl_xor(r, 16);
        r += __shfl_xor(r, 32);
        s[k] = r;
    }
    if ((tid & 63) < 16) {
#pragma unroll
        for (int k = 0; k < 9; ++k) part[wv][k][cc] = s[k];
    }
    __syncthreads();
    if (tid < 144) {
        const int k = tid >> 4, c2 = tid & 15;
        const float t4 = part[0][k][c2] + part[1][k][c2] +
                         part[2][k][c2] + part[3][k][c2];
        inv_norm[k][c2] = 1.0f / fmaxf(sqrtf(t4), 1e-12f);
    }
    __syncthreads();

    float invn[9];
#pragma unroll
    for (int k = 0; k < 9; ++k) invn[k] = inv_norm[k][cc];

    {
        int i = 0, j = g;
        if (j >= HH) { j -= HH; i = 1; }
        for (int p = g; p < P; p += 16) {
            const int base = ((i + 2) * 16 + (j + 1)) * 16 + cc;
            const float xp = xp_[base];
            float acc = 0.0f;
#pragma unroll
            for (int k = 0; k < 9; ++k) {
                const int off = ((k / 3) - 2) * 16 + (k % 3) - 1;
                const float v = xp * xp_[base + off * 16];
                const float u = fmaxf(v * invn[k], 1e-6f);
                acc += u * u * u;
            }
            pre[((size_t)b * P + p) * C + c0 + cc] =
                cbrtf(acc * (1.0f / 9.0f)) + xp;
            j += 2; ++i;
            if (j >= HH) { j -= HH; ++i; }
        }
    }
}

// ---------------------------------------------------------------------------
// K2: L2 normalize each (b,p) row; write f16 tokens in packed layout.
// ---------------------------------------------------------------------------
__global__ __launch_bounds__(256) void k_rownorm(const float* __restrict__ in,
                                                 _Float16* __restrict__ outP) {
    const int row = blockIdx.x;               // b*P + p
    const float* r = in + (size_t)row * C;
    const int tid = threadIdx.x;
    float vals[3];
    float s = 0.0f;
#pragma unroll
    for (int q = 0; q < 3; ++q) {
        vals[q] = r[tid + q * 256];
        s += vals[q] * vals[q];
    }
    __shared__ float partial[4];
    __shared__ float inv;
    __shared__ _Float16 nrm[C];
#pragma unroll
    for (int off = 32; off > 0; off >>= 1) s += __shfl_xor(s, off);
    if ((tid & 63) == 0) partial[tid >> 6] = s;
    __syncthreads();
    if (tid == 0)
        inv = 1.0f / fmaxf(sqrtf(partial[0] + partial[1] + partial[2] + partial[3]), 1e-12f);
    __syncthreads();
#pragma unroll
    for (int q = 0; q < 3; ++q)
        nrm[tid + q * 256] = (_Float16)(vals[q] * inv);
    __syncthreads();
    if (tid < 96) {
        const half8 v = *(const half8*)&nrm[tid * 8];
        const int kb = tid >> 2, s8 = tid & 3;   // c = tid*8
        *(half8*)&outP[(size_t)kb * TOK_KB + (row >> 5) * 1024 + s8 * 256 +
                       (row & 31) * 8] = v;
    }
}

// ---------------------------------------------------------------------------
// K2b: weight pack: W (K x N) f32 -> WtP packed [kb][rg][s][r][8] f16
// ---------------------------------------------------------------------------
__global__ __launch_bounds__(256) void k_wt(const float* __restrict__ W,
                                            _Float16* __restrict__ WtP) {
    __shared__ float tt[32][33];
    const int k0 = blockIdx.x * 32, n0 = blockIdx.y * 32;   // kb = blockIdx.x
    const int r = threadIdx.x / 32, c = threadIdx.x % 32;
#pragma unroll
    for (int q = 0; q < 4; ++q)
        tt[r + q * 8][c] = W[(size_t)(k0 + r + q * 8) * C + n0 + c];
    __syncthreads();
    const int nl = threadIdx.x >> 3, h = threadIdx.x & 7;
    const int n = n0 + nl;
    half4 v;
#pragma unroll
    for (int j = 0; j < 4; ++j) v[j] = (_Float16)tt[h * 4 + j][nl];
    *(half4*)&WtP[(size_t)blockIdx.x * WT_KB + (n >> 5) * 1024 +
                  (h >> 1) * 256 + (n & 31) * 8 + (h & 1) * 4] = v;
}

// ---------------------------------------------------------------------------
// K3/K4: f16 MFMA GEMM — NO LDS, NO barriers, direct global->VGPR fragment
// loads from the PACKED layout (each load = 4 x 256 B coalesced segments),
// with a 4-stage named register pipeline (W/X/Y/Z) whose interleave is
// PINNED by sched_group_barrier: [VMEM_READ x12][VMEM_READ x4, MFMA x4]x21
// [MFMA x4]x3.  This prevents the compiler from sinking loads to their use
// (R10's failure: VGPR=32, fully serialized).  3 stages (12 loads) stay in
// flight per wave -> dep-based waitcnt becomes counted vmcnt(12), never a
// drain.  Tile 64M x 64N, 4 waves (2x2 of 32x32), 24 K-steps, 4 MFMA/step.
// Grid 1176 1-D, XCD swizzle (one m-row's n-tiles per XCD; W L2-resident).
// GELU=true: output packed f16.  GELU=false: f32 row-major.
// ---------------------------------------------------------------------------
template <bool GELU>
__global__ __launch_bounds__(256, 4) void k_mfma_gemm(
    const _Float16* __restrict__ TokP,  // packed [24][196][4][32][8]  B-op
    const _Float16* __restrict__ WtP,   // packed [24][24][4][32][8]   A-op
    const float* __restrict__ bias,     // (N)
    void* __restrict__ Cout) {          // packed f16 (GELU) or f32 row-major
    const int tid = threadIdx.x;
    const int w = tid >> 6, l = tid & 63;
    const int l15 = l & 15, lk = l >> 4;

    // XCD swizzle: equal lid%8 (one XCD) covers one m-row's 12 n-tiles.
    const int lid = blockIdx.x;
    int vm, vn;
    if (lid < 1152) { vm = (lid / 96) * 8 + (lid & 7); vn = (lid % 96) >> 3; }
    else            { const int r = lid - 1152; vm = 96 + r / 12; vn = r % 12; }
    const int m0 = vm * 64, n0 = vn * 64;
    const int wn = (w & 1) * 32, wm = (w >> 1) * 32;

    f32x4 acc[2][2] = {};   // [fa over n][fb over m]

    // per-lane packed fragment base (chunk + lk*256 + l15*8); step t adds
    // t*WT_KB / t*TOK_KB.  a1/b1 = +16 rows = +128 elements.
    const _Float16* pA = WtP + (size_t)((n0 + wn) >> 5) * 1024 + lk * 256 + l15 * 8;
    const _Float16* pB = TokP + (size_t)((m0 + wm) >> 5) * 1024 + lk * 256 + l15 * 8;

#define LOADSET(s, t_)                                                         \
    {   const _Float16* cA = pA + (size_t)(t_) * WT_KB;                        \
        const _Float16* cB = pB + (size_t)(t_) * TOK_KB;                       \
        a0##s = *(const half8*)(cA);                                           \
        a1##s = *(const half8*)(cA + 128);                                     \
        b0##s = *(const half8*)(cB);                                           \
        b1##s = *(const half8*)(cB + 128); }
#define MFMASET(s)                                                             \
    {   acc[0][0] = __builtin_amdgcn_mfma_f32_16x16x32_f16(a0##s, b0##s, acc[0][0], 0, 0, 0); \
        acc[0][1] = __builtin_amdgcn_mfma_f32_16x16x32_f16(a0##s, b1##s, acc[0][1], 0, 0, 0); \
        acc[1][0] = __builtin_amdgcn_mfma_f32_16x16x32_f16(a1##s, b0##s, acc[1][0], 0, 0, 0); \
        acc[1][1] = __builtin_amdgcn_mfma_f32_16x16x32_f16(a1##s, b1##s, acc[1][1], 0, 0, 0); }
#define SGB_V4 __builtin_amdgcn_sched_group_barrier(0x020, 4, 0)
#define SGB_M4 __builtin_amdgcn_sched_group_barrier(0x008, 4, 0)

    half8 a0W, a1W, b0W, b1W, a0X, a1X, b0X, b1X;
    half8 a0Y, a1Y, b0Y, b1Y, a0Z, a1Z, b0Z, b1Z;

    LOADSET(W, 0); LOADSET(X, 1); LOADSET(Y, 2);
    __builtin_amdgcn_sched_group_barrier(0x020, 12, 0);
#pragma unroll
    for (int tt = 0; tt < 6; ++tt) {
        const int t = 4 * tt;
        LOADSET(Z, t + 3);
        MFMASET(W);
        SGB_V4; SGB_M4;
        if (tt < 5) {
            LOADSET(W, t + 4);
            MFMASET(X);
            SGB_V4; SGB_M4;
            LOADSET(X, t + 5);
            MFMASET(Y);
            SGB_V4; SGB_M4;
            LOADSET(Y, t + 6);
            MFMASET(Z);
            SGB_V4; SGB_M4;
        } else {
            MFMASET(X);
            SGB_M4;
            MFMASET(Y);
            SGB_M4;
            MFMASET(Z);
            SGB_M4;
        }
    }
#undef LOADSET
#undef MFMASET
#undef SGB_V4
#undef SGB_M4

    // epilogue: lane holds D[n = nb + r][m], r=0..3 consecutive n
#pragma unroll
    for (int fa = 0; fa < 2; ++fa) {
        const int nb = n0 + wn + fa * 16 + lk * 4;
        const float4 bv = *(const float4*)&bias[nb];
#pragma unroll
        for (int fb = 0; fb < 2; ++fb) {
            const int m = m0 + wm + fb * 16 + l15;
            if (GELU) {
                half4 o;
#pragma unroll
                for (int rr = 0; rr < 4; ++rr) {
                    float v = acc[fa][fb][rr] + ((const float*)&bv)[rr];
                    v = 0.5f * v * (1.0f + erff(v * 0.70710678118654752f));
                    o[rr] = (_Float16)v;
                }
                *(half4*)&((_Float16*)Cout)[(size_t)(nb >> 5) * TOK_KB +
                                            (m >> 5) * 1024 +
                                            ((nb >> 3) & 3) * 256 +
                                            (m & 31) * 8 + (nb & 7)] = o;
            } else {
                float4 o;
#pragma unroll
                for (int rr = 0; rr < 4; ++rr)
                    ((float*)&o)[rr] = acc[fa][fb][rr] + ((const float*)&bv)[rr];
                *(float4*)&((float*)Cout)[(size_t)m * C + nb] = o;
            }
        }
    }
}

// ---------------------------------------------------------------------------
// K5: GeM over tokens: g[b,c] = (mean_p clip(x,1e-6)^3)^(1/3)
// ---------------------------------------------------------------------------
__global__ __launch_bounds__(256) void k_gempool(const float* __restrict__ tk,
                                                 float* __restrict__ g) {
    const int b = blockIdx.x / 3;
    const int c = (blockIdx.x % 3) * 256 + threadIdx.x;
    float s = 0.0f;
#pragma unroll 4
    for (int p = 0; p < P; ++p) {
        const float v = fmaxf(tk[((size_t)b * P + p) * C + c], 1e-6f);
        s += v * v * v;
    }
    g[b * C + c] = cbrtf(s * (1.0f / (float)P));
}

// ---------------------------------------------------------------------------
// K6a: head GEMM stage 1 (split-K).  grid (NC/64, KSPLIT) = 1536 blocks.
// ---------------------------------------------------------------------------
__global__ __launch_bounds__(256) void k_head1(const float* __restrict__ g,
                                               const float* __restrict__ W,
                                               float* __restrict__ partial) {
    const int n0 = blockIdx.x * 64;
    const int k0 = blockIdx.y * 32;
    __shared__ float gs[32][32];          // [b][kk]
    __shared__ float part[4][32][64];     // [q][b][c]
    const int tid = threadIdx.x;

    for (int idx = tid; idx < 32 * 32; idx += 256)
        gs[idx >> 5][idx & 31] = g[(idx >> 5) * C + k0 + (idx & 31)];
    __syncthreads();

    const int c = tid & 63, q = tid >> 6;
    float acc[32] = {};
#pragma unroll
    for (int kk = 0; kk < 8; ++kk) {
        const int k = q * 8 + kk;
        const float wv = W[(size_t)(k0 + k) * NC + n0 + c];
#pragma unroll
        for (int b = 0; b < 32; ++b) acc[b] += gs[b][k] * wv;
    }
#pragma unroll
    for (int b = 0; b < 32; ++b) part[q][b][c] = acc[b];
    __syncthreads();

    for (int o = tid; o < 32 * 64; o += 256) {
        const int b = o >> 6, cc = o & 63;
        const float v = part[0][b][cc] + part[1][b][cc] +
                        part[2][b][cc] + part[3][b][cc];
        partial[((size_t)blockIdx.y * 32 + b) * NC + n0 + cc] = v;
    }
}

// ---------------------------------------------------------------------------
// K6b: head GEMM stage 2: fixed-order sum of KSPLIT partials + bias.
// ---------------------------------------------------------------------------
__global__ __launch_bounds__(256) void k_head2(const float* __restrict__ partial,
                                               const float* __restrict__ hb,
                                               float* __restrict__ out) {
    const int n = blockIdx.x * 256 + threadIdx.x;
    const int b = blockIdx.y;
    float s = hb[n];
#pragma unroll
    for (int ks = 0; ks < KSPLIT; ++ks)
        s += partial[((size_t)ks * 32 + b) * NC + n];
    out[(size_t)b * NC + n] = s;
}

// ---------------------------------------------------------------------------
// K7: L2-normalize each batch row of out (4096) in place.
// ---------------------------------------------------------------------------
__global__ __launch_bounds__(256) void k_outnorm(float* __restrict__ out) {
    const int b = blockIdx.x;
    float* r = out + (size_t)b * NC;
    const int tid = threadIdx.x;
    float v[16];
    float s = 0.0f;
#pragma unroll
    for (int q = 0; q < 16; ++q) {
        v[q] = r[tid + q * 256];
        s += v[q] * v[q];
    }
    __shared__ float partial[4];
    __shared__ float inv;
#pragma unroll
    for (int off = 32; off > 0; off >>= 1) s += __shfl_xor(s, off);
    if ((tid & 63) == 0) partial[tid >> 6] = s;
    __syncthreads();
    if (tid == 0)
        inv = 1.0f / fmaxf(sqrtf(partial[0] + partial[1] + partial[2] + partial[3]), 1e-12f);
    __syncthreads();
#pragma unroll
    for (int q = 0; q < 16; ++q) r[tid + q * 256] = v[q] * inv;
}

// ---------------------------------------------------------------------------
extern "C" void kernel_launch(void* const* d_in, const int* in_sizes, int n_in,
                              void* d_out, int out_size, void* d_ws, size_t ws_size,
                              hipStream_t stream) {
    const float* patch  = (const float*)d_in[0];
    const float* fc1_w  = (const float*)d_in[1];
    const float* fc1_b  = (const float*)d_in[2];
    const float* fc2_w  = (const float*)d_in[3];
    const float* fc2_b  = (const float*)d_in[4];
    const float* head_w = (const float*)d_in[5];
    const float* head_b = (const float*)d_in[6];
    float* out = (float*)d_out;

    const size_t big = (size_t)B * P * C;        // 4,816,896 elements
    float*    pre  = (float*)d_ws;               // [big] f32; later reused as tok2
    _Float16* tokP = (_Float16*)(pre + big);     // [big] f16 packed
    _Float16* hdnP = tokP + big;                 // [big] f16 packed
    _Float16* wt1  = hdnP + big;                 // [768*768] f16 packed
    _Float16* wt2  = wt1 + C * C;                // [768*768] f16 packed
    float*    gbuf = (float*)(wt2 + C * C);      // [32*768] f32
    float*    hpart = gbuf + B * C;              // [KSPLIT*32*4096] f32
    float*    tok2 = pre;                        // reuse

    // K1: SSA + fusion + residual -> pre
    k_ssa<<<dim3(C / 16, B), dim3(256), 0, stream>>>(patch, pre);
    // weight packs (independent)
    k_wt<<<dim3(C / 32, C / 32), dim3(256), 0, stream>>>(fc1_w, wt1);
    k_wt<<<dim3(C / 32, C / 32), dim3(256), 0, stream>>>(fc2_w, wt2);
    // K2: channel L2 norm -> tokP (f16 packed)
    k_rownorm<<<dim3(B * P), dim3(256), 0, stream>>>(pre, tokP);
    // K3: fc1 + gelu -> hdnP (f16 packed)
    k_mfma_gemm<true><<<dim3(1176), dim3(256), 0, stream>>>(
        tokP, wt1, fc1_b, hdnP);
    // K4: fc2 -> tok2 (f32 row-major)
    k_mfma_gemm<false><<<dim3(1176), dim3(256), 0, stream>>>(
        hdnP, wt2, fc2_b, tok2);
    // K5: GeM over tokens -> gbuf
    k_gempool<<<dim3(B * 3), dim3(256), 0, stream>>>(tok2, gbuf);
    // K6: head GEMM, split-K two-stage -> out (pre-normalized)
    k_head1<<<dim3(NC / 64, KSPLIT), dim3(256), 0, stream>>>(gbuf, head_w, hpart);
    k_head2<<<dim3(NC / 256, B), dim3(256), 0, stream>>>(hpart, head_b, out);
    // K7: normalize rows of out
    k_outnorm<<<dim3(B), dim3(256), 0, stream>>>(out);
}

// Round 15
// 96.312 us; speedup vs baseline: 1.3942x; 1.1677x over previous
//
#include <hip/hip_runtime.h>
#include <hip/hip_bf16.h>
#include <math.h>

// Problem dims (fixed by reference)
#define B   32
#define P   196      // hw tokens (14x14)
#define C   768
#define NC  4096
#define HH  14
#define KSPLIT 24    // 768 / 32
#define NT  12       // K tiles per GEMM (768 / 64)
#define M6  6272     // B*P
// Packed k-tiled layout (R11-bench, the measured-best GEMM operand format):
//   X[kb][row][k']  with kb = k>>5, k' = k&31.  One (kb, 64-row) chunk is
//   64*32*2B = 4 KB contiguous -> global_load_lds staging is fully
//   coalesced (lane l reads base + l*16B).
#define TW  (768 * 32)    // Wt packed kb stride (elements)
#define TM  (M6 * 32)     // Tok/hdn packed kb stride (elements)

typedef _Float16 half8 __attribute__((ext_vector_type(8)));
typedef _Float16 half4 __attribute__((ext_vector_type(4)));
typedef float f32x4 __attribute__((ext_vector_type(4)));

#define GLOAD_LDS16(g, l)                                                      \
    __builtin_amdgcn_global_load_lds(                                          \
        (const __attribute__((address_space(1))) void*)(g),                    \
        (__attribute__((address_space(3))) void*)(l), 16, 0, 0)

// ---------------------------------------------------------------------------
// K1: SpaceSelfAware + space_fusion + residual.  16-channel blocks (fast
// variant, R12): grid (48, 32) = 1536 (~6/CU, 19 KB LDS).  Zero-padded
// 16x16 spatial halo tile; branchless 9-tap window; incremental (i,j).
// ---------------------------------------------------------------------------
__global__ __launch_bounds__(256) void k_ssa(const float* __restrict__ t,
                                             float* __restrict__ pre) {
    const int b = blockIdx.y, c0 = blockIdx.x * 16;
    __shared__ float xp_[256 * 16];        // [(i+2)*16 + (j+1)][cc]  16 KB
    __shared__ float part[4][9][16];
    __shared__ float inv_norm[9][16];
    const int tid = threadIdx.x;
    const int cc = tid & 15, g = tid >> 4, wv = tid >> 6;

#pragma unroll
    for (int q = 0; q < 16; ++q) xp_[q * 256 + tid] = 0.0f;
    __syncthreads();

    for (int idx = tid; idx < 784; idx += 256) {
        const int p = idx >> 2, c = (idx & 3) * 4;
        const int i = p / HH, j = p % HH;
        *(float4*)&xp_[((i + 2) * 16 + (j + 1)) * 16 + c] =
            *(const float4*)&t[((size_t)b * P + p) * C + c0 + c];
    }
    __syncthreads();

    float s[9] = {};
    {
        int i = 0, j = g;
        if (j >= HH) { j -= HH; i = 1; }
        for (int p = g; p < P; p += 16) {
            const int base = ((i + 2) * 16 + (j + 1)) * 16 + cc;
            const float xp = xp_[base];
            const float xp2 = xp * xp;
#pragma unroll
            for (int k = 0; k < 9; ++k) {
                const int off = ((k / 3) - 2) * 16 + (k % 3) - 1;  // const
                const float nb = xp_[base + off * 16];
                s[k] += xp2 * nb * nb;
            }
            j += 2; ++i;
            if (j >= HH) { j -= HH; ++i; }
        }
    }
#pragma unroll
    for (int k = 0; k < 9; ++k) {
        float r = s[k];
        r += __shfl_xor(r, 16);
        r += __shfl_xor(r, 32);
        s[k] = r;
    }
    if ((tid & 63) < 16) {
#pragma unroll
        for (int k = 0; k < 9; ++k) part[wv][k][cc] = s[k];
    }
    __syncthreads();
    if (tid < 144) {
        const int k = tid >> 4, c2 = tid & 15;
        const float t4 = part[0][k][c2] + part[1][k][c2] +
                         part[2][k][c2] + part[3][k][c2];
        inv_norm[k][c2] = 1.0f / fmaxf(sqrtf(t4), 1e-12f);
    }
    __syncthreads();

    float invn[9];
#pragma unroll
    for (int k = 0; k < 9; ++k) invn[k] = inv_norm[k][cc];

    {
        int i = 0, j = g;
        if (j >= HH) { j -= HH; i = 1; }
        for (int p = g; p < P; p += 16) {
            const int base = ((i + 2) * 16 + (j + 1)) * 16 + cc;
            const float xp = xp_[base];
            float acc = 0.0f;
#pragma unroll
            for (int k = 0; k < 9; ++k) {
                const int off = ((k / 3) - 2) * 16 + (k % 3) - 1;
                const float v = xp * xp_[base + off * 16];
                const float u = fmaxf(v * invn[k], 1e-6f);
                acc += u * u * u;
            }
            pre[((size_t)b * P + p) * C + c0 + cc] =
                cbrtf(acc * (1.0f / 9.0f)) + xp;
            j += 2; ++i;
            if (j >= HH) { j -= HH; ++i; }
        }
    }
}

// ---------------------------------------------------------------------------
// K2: L2 normalize each (b,p) row over 768 channels; write f16 tokens in
// the R11 packed layout tokP[kb][row][k'] via LDS bounce (half8 stores).
// ---------------------------------------------------------------------------
__global__ __launch_bounds__(256) void k_rownorm(const float* __restrict__ in,
                                                 _Float16* __restrict__ outP) {
    const int row = blockIdx.x;               // b*P + p
    const float* r = in + (size_t)row * C;
    const int tid = threadIdx.x;
    float vals[3];
    float s = 0.0f;
#pragma unroll
    for (int q = 0; q < 3; ++q) {
        vals[q] = r[tid + q * 256];
        s += vals[q] * vals[q];
    }
    __shared__ float partial[4];
    __shared__ float inv;
    __shared__ _Float16 nrm[C];
#pragma unroll
    for (int off = 32; off > 0; off >>= 1) s += __shfl_xor(s, off);
    if ((tid & 63) == 0) partial[tid >> 6] = s;
    __syncthreads();
    if (tid == 0)
        inv = 1.0f / fmaxf(sqrtf(partial[0] + partial[1] + partial[2] + partial[3]), 1e-12f);
    __syncthreads();
#pragma unroll
    for (int q = 0; q < 3; ++q)
        nrm[tid + q * 256] = (_Float16)(vals[q] * inv);
    __syncthreads();
    if (tid < 96) {
        const half8 v = *(const half8*)&nrm[tid * 8];
        const int kb = tid >> 2;                 // c = tid*8, kb = c>>5
        *(half8*)&outP[(size_t)kb * TM + (size_t)row * 32 + (tid & 3) * 8] = v;
    }
}

// ---------------------------------------------------------------------------
// K2b: weight pack: W (K x N) f32 -> WtP packed [kb][n][32] f16
// ---------------------------------------------------------------------------
__global__ __launch_bounds__(256) void k_wt(const float* __restrict__ W,
                                            _Float16* __restrict__ WtP) {
    __shared__ float tt[32][33];
    const int k0 = blockIdx.x * 32, n0 = blockIdx.y * 32;   // kb = blockIdx.x
    const int r = threadIdx.x / 32, c = threadIdx.x % 32;
#pragma unroll
    for (int q = 0; q < 4; ++q)
        tt[r + q * 8][c] = W[(size_t)(k0 + r + q * 8) * C + n0 + c];
    __syncthreads();
    const int nl = threadIdx.x >> 3, h = threadIdx.x & 7;
    const int n = n0 + nl;
    half4 v;
#pragma unroll
    for (int j = 0; j < 4; ++j) v[j] = (_Float16)tt[h * 4 + j][nl];
    *(half4*)&WtP[(size_t)blockIdx.x * TW + (size_t)n * 32 + h * 4] = v;
}

// ---------------------------------------------------------------------------
// K3/K4: f16 MFMA GEMM — the R11-bench measured-best structure, verbatim:
// 3-deep counted-vmcnt pipeline, barriers, 64M x 64N tile, BK=64, packed
// k-tiled operands so every global_load_lds is fully coalesced (4 KB
// contiguous chunks).  LDS 48 KB -> 3 blocks/CU.  Grid 1176 1-D with XCD
// swizzle (one m-row's 12 n-tiles per XCD).
// GELU=true: output hdn packed f16.  GELU=false: f32 row-major.
// ---------------------------------------------------------------------------
template <bool GELU>
__global__ __launch_bounds__(256) void k_mfma_gemm(
    const _Float16* __restrict__ TokP,  // packed (24 x M6 x 32)  B-operand
    const _Float16* __restrict__ WtP,   // packed (24 x 768 x 32) A-operand
    const float* __restrict__ bias,     // (N)
    void* __restrict__ Cout) {          // packed f16 (GELU) or f32 row-major
    __shared__ _Float16 lA[3][2][64][32];  // [buf][kb][n][k']
    __shared__ _Float16 lB[3][2][64][32];  // [buf][kb][m][k']
    const int tid = threadIdx.x;
    const int w = tid >> 6, l = tid & 63;
    const int l15 = l & 15, lk = l >> 4;

    // XCD swizzle: equal lid%8 (one XCD) covers one m-row's 12 n-tiles.
    const int lid = blockIdx.x;
    int vm, vn;
    if (lid < 1152) { vm = (lid / 96) * 8 + (lid & 7); vn = (lid % 96) >> 3; }
    else            { const int r = lid - 1152; vm = 96 + r / 12; vn = r % 12; }
    const int m0 = vm * 64, n0 = vn * 64;
    const int wn = (w & 1) * 32, wm = (w >> 1) * 32;

    f32x4 acc[2][2] = {};   // [fa over n][fb over m]

    // wave w stages one 4 KB chunk per stage: w<2 -> A (kb = w&1), else B
    const int kbsel = w & 1;
    const bool isB = (w >= 2);
    const _Float16* srcBase =
        isB ? (TokP + (size_t)m0 * 32) : (WtP + (size_t)n0 * 32);
    const size_t tileStride = isB ? (size_t)TM : (size_t)TW;
    _Float16* dst0 = isB ? &lB[0][kbsel][0][0] : &lA[0][kbsel][0][0];

#define ISSUE(tt, bf_)                                                         \
    {   const _Float16* s_ = srcBase + (size_t)(2 * (tt) + kbsel) * tileStride;\
        _Float16* d_ = dst0 + (size_t)(bf_) * 4096;                            \
        GLOAD_LDS16(s_ + l * 8,        d_ + l * 8);                            \
        GLOAD_LDS16(s_ + 512 + l * 8,  d_ + 512 + l * 8);                      \
        GLOAD_LDS16(s_ + 1024 + l * 8, d_ + 1024 + l * 8);                     \
        GLOAD_LDS16(s_ + 1536 + l * 8, d_ + 1536 + l * 8); }

    ISSUE(0, 0); ISSUE(1, 1); ISSUE(2, 2);   // 12 loads in flight / wave

    for (int t = 0; t < NT; ++t) {
        // own-wave tile-t loads complete; t+1, t+2 remain in flight
        if (t < NT - 2)       asm volatile("s_waitcnt vmcnt(8)" ::: "memory");
        else if (t == NT - 2) asm volatile("s_waitcnt vmcnt(4)" ::: "memory");
        else                  asm volatile("s_waitcnt vmcnt(0)" ::: "memory");
        __builtin_amdgcn_s_barrier();          // all waves' tile-t loads done
        __builtin_amdgcn_sched_barrier(0);     // no ds_read hoisted above

        const int buf = t % 3;
#pragma unroll
        for (int kk = 0; kk < 2; ++kk) {       // two 32-k sub-steps (kb tiles)
            half8 af[2], bf[2];
#pragma unroll
            for (int fa = 0; fa < 2; ++fa)
                af[fa] = *(const half8*)&lA[buf][kk][wn + fa * 16 + l15][lk * 8];
#pragma unroll
            for (int fb = 0; fb < 2; ++fb)
                bf[fb] = *(const half8*)&lB[buf][kk][wm + fb * 16 + l15][lk * 8];
#pragma unroll
            for (int fa = 0; fa < 2; ++fa)
#pragma unroll
                for (int fb = 0; fb < 2; ++fb)
                    acc[fa][fb] = __builtin_amdgcn_mfma_f32_16x16x32_f16(
                        af[fa], bf[fb], acc[fa][fb], 0, 0, 0);
        }
        asm volatile("s_waitcnt lgkmcnt(0)" ::: "memory");  // reads retired
        __builtin_amdgcn_s_barrier();          // safe to overwrite buf
        __builtin_amdgcn_sched_barrier(0);
        if (t < NT - 3) ISSUE(t + 3, buf);     // refill; stays in flight
    }
#undef ISSUE

    // epilogue: lane holds D[n = nb + r][m], r=0..3 consecutive n
#pragma unroll
    for (int fa = 0; fa < 2; ++fa) {
        const int nb = n0 + wn + fa * 16 + lk * 4;
        const float4 bv = *(const float4*)&bias[nb];
#pragma unroll
        for (int fb = 0; fb < 2; ++fb) {
            const int m = m0 + wm + fb * 16 + l15;
            if (GELU) {
                half4 o;
#pragma unroll
                for (int rr = 0; rr < 4; ++rr) {
                    float v = acc[fa][fb][rr] + ((const float*)&bv)[rr];
                    v = 0.5f * v * (1.0f + erff(v * 0.70710678118654752f));
                    o[rr] = (_Float16)v;
                }
                // packed write: hdnP[kb = nb>>5][m][k' = nb&31 .. +3]
                *(half4*)&((_Float16*)Cout)[(size_t)(nb >> 5) * TM +
                                            (size_t)m * 32 + (nb & 31)] = o;
            } else {
                float4 o;
#pragma unroll
                for (int rr = 0; rr < 4; ++rr)
                    ((float*)&o)[rr] = acc[fa][fb][rr] + ((const float*)&bv)[rr];
                *(float4*)&((float*)Cout)[(size_t)m * C + nb] = o;
            }
        }
    }
}

// ---------------------------------------------------------------------------
// K5: GeM over tokens: g[b,c] = (mean_p clip(x,1e-6)^3)^(1/3)
// grid (B*12) = 384 blocks: block = (b, 64-channel tile); 4 token-groups
// of 64 threads each sum 49 tokens; fixed-order LDS combine.
// ---------------------------------------------------------------------------
__global__ __launch_bounds__(256) void k_gempool(const float* __restrict__ tk,
                                                 float* __restrict__ g) {
    const int b = blockIdx.x / 12;
    const int c0 = (blockIdx.x % 12) * 64;
    const int tid = threadIdx.x;
    const int cc = tid & 63, pg = tid >> 6;
    float s = 0.0f;
    for (int p = pg * 49; p < pg * 49 + 49; ++p) {
        const float v = fmaxf(tk[((size_t)b * P + p) * C + c0 + cc], 1e-6f);
        s += v * v * v;
    }
    __shared__ float part[4][64];
    part[pg][cc] = s;
    __syncthreads();
    if (tid < 64) {
        const float t4 = part[0][cc] + part[1][cc] + part[2][cc] + part[3][cc];
        g[b * C + c0 + cc] = cbrtf(t4 * (1.0f / (float)P));
    }
}

// ---------------------------------------------------------------------------
// K6a: head GEMM stage 1 (split-K).  grid (NC/64, KSPLIT) = 1536 blocks.
// ---------------------------------------------------------------------------
__global__ __launch_bounds__(256) void k_head1(const float* __restrict__ g,
                                               const float* __restrict__ W,
                                               float* __restrict__ partial) {
    const int n0 = blockIdx.x * 64;
    const int k0 = blockIdx.y * 32;
    __shared__ float gs[32][32];          // [b][kk]
    __shared__ float part[4][32][64];     // [q][b][c]
    const int tid = threadIdx.x;

    for (int idx = tid; idx < 32 * 32; idx += 256)
        gs[idx >> 5][idx & 31] = g[(idx >> 5) * C + k0 + (idx & 31)];
    __syncthreads();

    const int c = tid & 63, q = tid >> 6;
    float acc[32] = {};
#pragma unroll
    for (int kk = 0; kk < 8; ++kk) {
        const int k = q * 8 + kk;
        const float wv = W[(size_t)(k0 + k) * NC + n0 + c];
#pragma unroll
        for (int b = 0; b < 32; ++b) acc[b] += gs[b][k] * wv;
    }
#pragma unroll
    for (int b = 0; b < 32; ++b) part[q][b][c] = acc[b];
    __syncthreads();

    for (int o = tid; o < 32 * 64; o += 256) {
        const int b = o >> 6, cc = o & 63;
        const float v = part[0][b][cc] + part[1][b][cc] +
                        part[2][b][cc] + part[3][b][cc];
        partial[((size_t)blockIdx.y * 32 + b) * NC + n0 + cc] = v;
    }
}

// ---------------------------------------------------------------------------
// K6b: head GEMM stage 2: fixed-order sum of KSPLIT partials + bias.
// ---------------------------------------------------------------------------
__global__ __launch_bounds__(256) void k_head2(const float* __restrict__ partial,
                                               const float* __restrict__ hb,
                                               float* __restrict__ out) {
    const int n = blockIdx.x * 256 + threadIdx.x;
    const int b = blockIdx.y;
    float s = hb[n];
#pragma unroll
    for (int ks = 0; ks < KSPLIT; ++ks)
        s += partial[((size_t)ks * 32 + b) * NC + n];
    out[(size_t)b * NC + n] = s;
}

// ---------------------------------------------------------------------------
// K7: L2-normalize each batch row of out (4096) in place.
// ---------------------------------------------------------------------------
__global__ __launch_bounds__(256) void k_outnorm(float* __restrict__ out) {
    const int b = blockIdx.x;
    float* r = out + (size_t)b * NC;
    const int tid = threadIdx.x;
    float v[16];
    float s = 0.0f;
#pragma unroll
    for (int q = 0; q < 16; ++q) {
        v[q] = r[tid + q * 256];
        s += v[q] * v[q];
    }
    __shared__ float partial[4];
    __shared__ float inv;
#pragma unroll
    for (int off = 32; off > 0; off >>= 1) s += __shfl_xor(s, off);
    if ((tid & 63) == 0) partial[tid >> 6] = s;
    __syncthreads();
    if (tid == 0)
        inv = 1.0f / fmaxf(sqrtf(partial[0] + partial[1] + partial[2] + partial[3]), 1e-12f);
    __syncthreads();
#pragma unroll
    for (int q = 0; q < 16; ++q) r[tid + q * 256] = v[q] * inv;
}

// ---------------------------------------------------------------------------
extern "C" void kernel_launch(void* const* d_in, const int* in_sizes, int n_in,
                              void* d_out, int out_size, void* d_ws, size_t ws_size,
                              hipStream_t stream) {
    const float* patch  = (const float*)d_in[0];
    const float* fc1_w  = (const float*)d_in[1];
    const float* fc1_b  = (const float*)d_in[2];
    const float* fc2_w  = (const float*)d_in[3];
    const float* fc2_b  = (const float*)d_in[4];
    const float* head_w = (const float*)d_in[5];
    const float* head_b = (const float*)d_in[6];
    float* out = (float*)d_out;

    const size_t big = (size_t)B * P * C;        // 4,816,896 elements
    float*    pre  = (float*)d_ws;               // [big] f32; later reused as tok2
    _Float16* tokP = (_Float16*)(pre + big);     // [big] f16 packed
    _Float16* hdnP = tokP + big;                 // [big] f16 packed
    _Float16* wt1  = hdnP + big;                 // [768*768] f16 packed
    _Float16* wt2  = wt1 + C * C;                // [768*768] f16 packed
    float*    gbuf = (float*)(wt2 + C * C);      // [32*768] f32
    float*    hpart = gbuf + B * C;              // [KSPLIT*32*4096] f32
    float*    tok2 = pre;                        // reuse

    // K1: SSA + fusion + residual -> pre
    k_ssa<<<dim3(C / 16, B), dim3(256), 0, stream>>>(patch, pre);
    // weight packs (independent)
    k_wt<<<dim3(C / 32, C / 32), dim3(256), 0, stream>>>(fc1_w, wt1);
    k_wt<<<dim3(C / 32, C / 32), dim3(256), 0, stream>>>(fc2_w, wt2);
    // K2: channel L2 norm -> tokP (f16 packed)
    k_rownorm<<<dim3(B * P), dim3(256), 0, stream>>>(pre, tokP);
    // K3: fc1 + gelu -> hdnP (f16 packed)
    k_mfma_gemm<true><<<dim3(1176), dim3(256), 0, stream>>>(
        tokP, wt1, fc1_b, hdnP);
    // K4: fc2 -> tok2 (f32 row-major)
    k_mfma_gemm<false><<<dim3(1176), dim3(256), 0, stream>>>(
        hdnP, wt2, fc2_b, tok2);
    // K5: GeM over tokens -> gbuf
    k_gempool<<<dim3(B * 12), dim3(256), 0, stream>>>(tok2, gbuf);
    // K6: head GEMM, split-K two-stage -> out (pre-normalized)
    k_head1<<<dim3(NC / 64, KSPLIT), dim3(256), 0, stream>>>(gbuf, head_w, hpart);
    k_head2<<<dim3(NC / 256, B), dim3(256), 0, stream>>>(hpart, head_b, out);
    // K7: normalize rows of out
    k_outnorm<<<dim3(B), dim3(256), 0, stream>>>(out);
}